// Round 20
// baseline (84.931 us; speedup 1.0000x reference)
//
#include <hip/hip_runtime.h>
#include <stdint.h>

#define TB 2048
#define NEL ((size_t)4 * TB * 256)   // elements of one [B*T,256] bf16 buffer

typedef __attribute__((ext_vector_type(4))) float f32x4;
typedef __attribute__((ext_vector_type(8))) short short8;

__device__ __forceinline__ unsigned short f2bf(float f) {
  union { float f; unsigned u; } v; v.f = f;
  unsigned r = v.u + 0x7fffu + ((v.u >> 16) & 1u);
  return (unsigned short)(r >> 16);
}
__device__ __forceinline__ unsigned cvtpk(float lo, float hi) {
  unsigned r;
  asm("v_cvt_pk_bf16_f32 %0, %1, %2" : "=v"(r) : "v"(lo), "v"(hi));
  return r;
}
__device__ __forceinline__ float bf2f(unsigned short u) {
  union { unsigned u; float f; } v; v.u = ((unsigned)u) << 16;
  return v.f;
}

// ---------------- kernel 1: tables ----------------
// td2[d] = alpha*eta/(1+d^|beta|) * (1/sqrt(32)) * log2(e)   (all scales folded)
// ocT[b][c][t] = oc[b][t][c]
__global__ void k_tables(const float* __restrict__ eta, const float* __restrict__ beta,
                         const float* __restrict__ alpha, const float* __restrict__ oc,
                         float* __restrict__ td2, float* __restrict__ ocT) {
  int i = blockIdx.x * 256 + threadIdx.x;  // 2048 threads
  if (i < TB) {
    float ab = fabsf(beta[0]);
    float dt = powf((float)i, ab);
    td2[i] = alpha[0] * eta[0] / (1.0f + dt) * 0.17677669529663687f * 1.4426950408889634f;
  }
  for (int j = i; j < 4 * 3 * TB; j += 2048) {
    int b = j / (3 * TB);
    int r = j - b * 3 * TB;
    int c = r / TB;
    int t = r - c * TB;
    ocT[j] = oc[((size_t)b * TB + t) * 3 + c];
  }
}

// ---------------- kernel 2: QKV projection ----------------
__global__ __launch_bounds__(256, 2) void k_proj(
    const float* __restrict__ x,
    const float* __restrict__ Wq, const float* __restrict__ bq,
    const float* __restrict__ Wk, const float* __restrict__ bk,
    const float* __restrict__ Wv, const float* __restrict__ bv,
    unsigned short* __restrict__ Qb, unsigned short* __restrict__ Kb,
    unsigned short* __restrict__ Vtb) {
  __shared__ unsigned short Al[64 * 256];
  __shared__ unsigned short Bl[64 * 256];
  const int m0 = blockIdx.x * 64, n0 = blockIdx.y * 64, z = blockIdx.z;
  const int tid = threadIdx.x;
  const float* W = (z == 0) ? Wq : (z == 1) ? Wk : Wv;
  const float* bias = (z == 0) ? bq : (z == 1) ? bk : bv;

#pragma unroll
  for (int it = 0; it < 8; ++it) {
    int C = it * 256 + tid;
    int row = C >> 5, lc = C & 31;
    const float4* ga = (const float4*)(x + (size_t)(m0 + row) * 256 + lc * 8);
    float4 a0 = ga[0], a1 = ga[1];
    uint4 pa;
    pa.x = cvtpk(a0.x, a0.y); pa.y = cvtpk(a0.z, a0.w);
    pa.z = cvtpk(a1.x, a1.y); pa.w = cvtpk(a1.z, a1.w);
    *(uint4*)&Al[row * 256 + ((lc ^ (row & 7)) * 8)] = pa;
    const float4* gb = (const float4*)(W + (size_t)(n0 + row) * 256 + lc * 8);
    float4 b0 = gb[0], b1 = gb[1];
    uint4 pb;
    pb.x = cvtpk(b0.x, b0.y); pb.y = cvtpk(b0.z, b0.w);
    pb.z = cvtpk(b1.x, b1.y); pb.w = cvtpk(b1.z, b1.w);
    *(uint4*)&Bl[row * 256 + ((lc ^ (row & 7)) * 8)] = pb;
  }
  __syncthreads();

  const int w = tid >> 6, l = tid & 63, g = l >> 4, ql = l & 15;
  const int wm = w >> 1, wn = w & 1;
  f32x4 acc[2][2] = {};
#pragma unroll
  for (int kk = 0; kk < 8; ++kk) {
    short8 af[2], bf_[2];
#pragma unroll
    for (int mi = 0; mi < 2; ++mi) {
      int row = wm * 32 + mi * 16 + ql;
      af[mi] = *(const short8*)&Al[row * 256 + (((kk * 4 + g) ^ (row & 7)) * 8)];
    }
#pragma unroll
    for (int ni = 0; ni < 2; ++ni) {
      int row = wn * 32 + ni * 16 + ql;
      bf_[ni] = *(const short8*)&Bl[row * 256 + (((kk * 4 + g) ^ (row & 7)) * 8)];
    }
#pragma unroll
    for (int mi = 0; mi < 2; ++mi)
#pragma unroll
      for (int ni = 0; ni < 2; ++ni)
        acc[mi][ni] = __builtin_amdgcn_mfma_f32_16x16x32_bf16(af[mi], bf_[ni], acc[mi][ni], 0, 0, 0);
  }

#pragma unroll
  for (int ni = 0; ni < 2; ++ni) {
    int n = n0 + wn * 32 + ni * 16 + ql;
    float bs = bias[n];
#pragma unroll
    for (int mi = 0; mi < 2; ++mi) {
      int mb = m0 + wm * 32 + mi * 16 + 4 * g;
      f32x4 v = acc[mi][ni];
      v.x += bs; v.y += bs; v.z += bs; v.w += bs;
      if (z == 2) {
        int batch = mb >> 11, t = mb & 2047;
        uint2 pv; pv.x = cvtpk(v.x, v.y); pv.y = cvtpk(v.z, v.w);
        *(uint2*)&Vtb[(size_t)(batch * 256 + n) * 2048 + t] = pv;
      } else {
        unsigned short* dst = (z == 0) ? Qb : Kb;
        dst[(size_t)(mb + 0) * 256 + n] = f2bf(v.x);
        dst[(size_t)(mb + 1) * 256 + n] = f2bf(v.y);
        dst[(size_t)(mb + 2) * 256 + n] = f2bf(v.z);
        dst[(size_t)(mb + 3) * 256 + n] = f2bf(v.w);
      }
    }
  }
}

// softmax for one q-halfwave: consumes s[4] (f32x4), writes Pl, accumulates srow
#define SOFTMAX_Q(QQ, SARR, SROW)                                             \
  do {                                                                        \
    const int qg_ = q0 + (QQ);                                                \
    float ssum_ = 0.f;                                                        \
    _Pragma("unroll") for (int kb = 0; kb < 4; ++kb) {                        \
      f32x4 pr = *(const f32x4*)&Pr[par][(QQ) * 64 + (((kb * 4 + g) ^ ql) * 4)]; \
      f32x4 s2;                                                               \
      s2.x = SARR[kb].x * pr.x; s2.y = SARR[kb].y * pr.y;                     \
      s2.z = SARR[kb].z * pr.z; s2.w = SARR[kb].w * pr.w;                     \
      if (diag) {                                                             \
        int kbase = k0 + kb * 16 + 4 * g;                                     \
        if (kbase + 0 > qg_) s2.x = -__builtin_inff();                        \
        if (kbase + 1 > qg_) s2.y = -__builtin_inff();                        \
        if (kbase + 2 > qg_) s2.z = -__builtin_inff();                        \
        if (kbase + 3 > qg_) s2.w = -__builtin_inff();                        \
      }                                                                       \
      f32x4 p;                                                                \
      p.x = exp2f(s2.x); p.y = exp2f(s2.y);                                   \
      p.z = exp2f(s2.z); p.w = exp2f(s2.w);                                   \
      ssum_ += (p.x + p.y) + (p.z + p.w);                                     \
      uint2 pp; pp.x = cvtpk(p.x, p.y); pp.y = cvtpk(p.z, p.w);               \
      int c16 = 2 * kb + (g >> 1);                                            \
      *(uint2*)&Pl[w][(QQ) * 64 + ((c16 ^ ((QQ) & 7)) * 8) + (g & 1) * 4] = pp; \
    }                                                                         \
    SROW += ssum_;                                                            \
  } while (0)

// ---------------- kernel 3: fused causal attention with prior ----------------
// R9 schedule (NSLOT=4 balanced pairing). Changes vs R9 body:
//  (1) __launch_bounds__(512, 2): lets allocator exceed 64 VGPRs (<=128 keeps
//      2 blocks/CU with 48KB LDS) instead of spilling (R10/R18 lesson).
//  (2) V fragment loads hoisted to right after qb=1's QK^T MFMAs (where kf
//      dies, net liveness -16): their L2 latency hides under qb=1's softmax
//      instead of sitting exposed after the lgkmcnt fence.
template <int NSLOT>
__global__ __launch_bounds__(512, 2) void k_attn(
    const unsigned short* __restrict__ Qb, const unsigned short* __restrict__ Kb,
    const unsigned short* __restrict__ Vtb, const float* __restrict__ oc,
    const float* __restrict__ ocT, const float* __restrict__ td2,
    unsigned short* __restrict__ Op, float* __restrict__ MS) {
  __shared__ unsigned short Pl[8][32 * 64]; // 32KB per-wave P [q][k]
  __shared__ float Pr[2][32 * 64];          // 16KB dbuf prior [q][k]
  const int bx = blockIdx.x, bb = blockIdx.y;
  const int ip   = (NSLOT == 4) ? (bx >> 2) : (NSLOT == 2) ? (bx >> 1) : bx;
  const int slot = (NSLOT == 4) ? (bx & 3)  : (NSLOT == 2) ? (bx & 1)  : 0;
  const int tid = threadIdx.x;
  const int w = tid >> 6, l = tid & 63, g = l >> 4, ql = l & 15;
  const int h = w;
  const f32x4 zero4 = {0.f, 0.f, 0.f, 0.f};
  const int pq = tid & 31, pck = tid >> 5;  // prior mapping: q-row, 4-wide k-chunk

  int par = 0;  // Pr buffer parity, carried across segments

#pragma unroll 1
  for (int seg = 0; seg < 2; ++seg) {
    if (NSLOT == 1 && seg == 1) break;
    const int qt = (NSLOT == 1) ? (63 - bx) : (seg ? ip : (63 - ip));
    const int q0 = qt * 32;
    const int nst = (qt + 2) >> 1;
    const int sb = (NSLOT == 1) ? 0 : (slot * nst) / NSLOT;
    const int se = (NSLOT == 1) ? nst : ((slot + 1) * nst) / NSLOT;

    short8 qf[2];
#pragma unroll
    for (int qb = 0; qb < 2; ++qb)
      qf[qb] = *(const short8*)&Qb[(size_t)(bb * TB + q0 + qb * 16 + ql) * 256 + h * 32 + 8 * g];

    const float oq0 = oc[(size_t)(bb * TB + q0 + pq) * 3 + 0];
    const float oq1 = oc[(size_t)(bb * TB + q0 + pq) * 3 + 1];
    const float oq2 = oc[(size_t)(bb * TB + q0 + pq) * 3 + 2];

    f32x4 oacc[2][2] = {};   // [db][qb]
    float srow[2] = {0.f, 0.f};

    for (int st = sb; st < se; ++st, par ^= 1) {
      const int k0 = st * 64;
      // K fragments for THIS step, direct from global (L2-resident)
      short8 kf0 = *(const short8*)&Kb[(size_t)(bb * TB + k0 + 0 * 16 + ql) * 256 + h * 32 + 8 * g];
      short8 kf1 = *(const short8*)&Kb[(size_t)(bb * TB + k0 + 1 * 16 + ql) * 256 + h * 32 + 8 * g];
      short8 kf2 = *(const short8*)&Kb[(size_t)(bb * TB + k0 + 2 * 16 + ql) * 256 + h * 32 + 8 * g];
      short8 kf3 = *(const short8*)&Kb[(size_t)(bb * TB + k0 + 3 * 16 + ql) * 256 + h * 32 + 8 * g];
      // prior tile [32q][64k] (shared by all 8 heads), vectorized ocT loads
      {
        const float* o0 = &ocT[(size_t)bb * 3 * TB + k0 + pck * 4];
        float4 a = *(const float4*)o0;
        float4 b2 = *(const float4*)(o0 + TB);
        float4 c2 = *(const float4*)(o0 + 2 * TB);
        const int qi = q0 + pq - k0 - pck * 4;
        float pv0, pv1, pv2, pv3;
        {
          float d0 = oq0 - a.x, d1 = oq1 - b2.x, d2 = oq2 - c2.x;
          int dd = qi; dd = dd < 0 ? -dd : dd;
          pv0 = td2[dd] * __expf(-(d0 * d0 + d1 * d1 + d2 * d2));
        }
        {
          float d0 = oq0 - a.y, d1 = oq1 - b2.y, d2 = oq2 - c2.y;
          int dd = qi - 1; dd = dd < 0 ? -dd : dd;
          pv1 = td2[dd] * __expf(-(d0 * d0 + d1 * d1 + d2 * d2));
        }
        {
          float d0 = oq0 - a.z, d1 = oq1 - b2.z, d2 = oq2 - c2.z;
          int dd = qi - 2; dd = dd < 0 ? -dd : dd;
          pv2 = td2[dd] * __expf(-(d0 * d0 + d1 * d1 + d2 * d2));
        }
        {
          float d0 = oq0 - a.w, d1 = oq1 - b2.w, d2 = oq2 - c2.w;
          int dd = qi - 3; dd = dd < 0 ? -dd : dd;
          pv3 = td2[dd] * __expf(-(d0 * d0 + d1 * d1 + d2 * d2));
        }
        f32x4 pvv = {pv0, pv1, pv2, pv3};
        *(f32x4*)&Pr[par][pq * 64 + ((pck ^ (pq & 15)) * 4)] = pvv;
      }
      __syncthreads();

      const bool diag = (k0 + 64 > q0);
      // ---- qb=0: QK^T + softmax (kf still live for qb=1) ----
      {
        f32x4 s[4];
        s[0] = __builtin_amdgcn_mfma_f32_16x16x32_bf16(kf0, qf[0], zero4, 0, 0, 0);
        s[1] = __builtin_amdgcn_mfma_f32_16x16x32_bf16(kf1, qf[0], zero4, 0, 0, 0);
        s[2] = __builtin_amdgcn_mfma_f32_16x16x32_bf16(kf2, qf[0], zero4, 0, 0, 0);
        s[3] = __builtin_amdgcn_mfma_f32_16x16x32_bf16(kf3, qf[0], zero4, 0, 0, 0);
        SOFTMAX_Q(ql, s, srow[0]);
      }
      // ---- qb=1: QK^T, then V loads (kf dies here), then softmax ----
      short8 vf00, vf01, vf10, vf11;
      {
        f32x4 s[4];
        s[0] = __builtin_amdgcn_mfma_f32_16x16x32_bf16(kf0, qf[1], zero4, 0, 0, 0);
        s[1] = __builtin_amdgcn_mfma_f32_16x16x32_bf16(kf1, qf[1], zero4, 0, 0, 0);
        s[2] = __builtin_amdgcn_mfma_f32_16x16x32_bf16(kf2, qf[1], zero4, 0, 0, 0);
        s[3] = __builtin_amdgcn_mfma_f32_16x16x32_bf16(kf3, qf[1], zero4, 0, 0, 0);
        // V fragment loads: latency hides under the softmax below
        vf00 = *(const short8*)&Vtb[(size_t)(bb * 256 + h * 32 + ql) * 2048 + k0 + 8 * g];
        vf01 = *(const short8*)&Vtb[(size_t)(bb * 256 + h * 32 + 16 + ql) * 2048 + k0 + 8 * g];
        vf10 = *(const short8*)&Vtb[(size_t)(bb * 256 + h * 32 + ql) * 2048 + k0 + 32 + 8 * g];
        vf11 = *(const short8*)&Vtb[(size_t)(bb * 256 + h * 32 + 16 + ql) * 2048 + k0 + 32 + 8 * g];
        SOFTMAX_Q(16 + ql, s, srow[1]);
      }
      // this wave's P writes -> visible to its own cross-lane reads
      asm volatile("s_waitcnt lgkmcnt(0)" ::: "memory");

      // ---- PV: O^T[d][q] += sum_k V^T[d][k] * P[q][k] ----
      {
        short8 pf0 = *(const short8*)&Pl[w][(ql) * 64 + (((0 + g) ^ (ql & 7)) * 8)];
        short8 pf1 = *(const short8*)&Pl[w][(16 + ql) * 64 + (((0 + g) ^ (ql & 7)) * 8)];
        oacc[0][0] = __builtin_amdgcn_mfma_f32_16x16x32_bf16(vf00, pf0, oacc[0][0], 0, 0, 0);
        oacc[0][1] = __builtin_amdgcn_mfma_f32_16x16x32_bf16(vf00, pf1, oacc[0][1], 0, 0, 0);
        oacc[1][0] = __builtin_amdgcn_mfma_f32_16x16x32_bf16(vf01, pf0, oacc[1][0], 0, 0, 0);
        oacc[1][1] = __builtin_amdgcn_mfma_f32_16x16x32_bf16(vf01, pf1, oacc[1][1], 0, 0, 0);
      }
      {
        short8 pf0 = *(const short8*)&Pl[w][(ql) * 64 + (((4 + g) ^ (ql & 7)) * 8)];
        short8 pf1 = *(const short8*)&Pl[w][(16 + ql) * 64 + (((4 + g) ^ (ql & 7)) * 8)];
        oacc[0][0] = __builtin_amdgcn_mfma_f32_16x16x32_bf16(vf10, pf0, oacc[0][0], 0, 0, 0);
        oacc[0][1] = __builtin_amdgcn_mfma_f32_16x16x32_bf16(vf10, pf1, oacc[0][1], 0, 0, 0);
        oacc[1][0] = __builtin_amdgcn_mfma_f32_16x16x32_bf16(vf11, pf0, oacc[1][0], 0, 0, 0);
        oacc[1][1] = __builtin_amdgcn_mfma_f32_16x16x32_bf16(vf11, pf1, oacc[1][1], 0, 0, 0);
      }
    }

    // ---- epilogue for this segment ----
#pragma unroll
    for (int qb = 0; qb < 2; ++qb) {
      float s_ = srow[qb];
      s_ += __shfl_xor(s_, 16);
      s_ += __shfl_xor(s_, 32);
      int qq = qb * 16 + ql;
      size_t m = (size_t)bb * TB + q0 + qq;
      if (NSLOT == 1) {
        float rinv = 1.0f / s_;
#pragma unroll
        for (int db = 0; db < 2; ++db) {
          f32x4 v = oacc[db][qb];
          uint2 pv2;
          pv2.x = cvtpk(v.x * rinv, v.y * rinv);
          pv2.y = cvtpk(v.z * rinv, v.w * rinv);
          *(uint2*)&Op[m * 256 + h * 32 + db * 16 + 4 * g] = pv2;
        }
      } else {
#pragma unroll
        for (int db = 0; db < 2; ++db) {
          f32x4 v = oacc[db][qb];
          uint2 pv2;
          pv2.x = cvtpk(v.x, v.y);
          pv2.y = cvtpk(v.z, v.w);
          *(uint2*)&Op[(size_t)slot * NEL + m * 256 + h * 32 + db * 16 + 4 * g] = pv2;
        }
        if (g == 0) MS[(size_t)slot * 65536 + m * 8 + h] = s_;
      }
    }
  }
}

// ---------------- kernel 4: output projection (+ NH-way merge folded in) ----
template <int NH>
__global__ __launch_bounds__(256, 2) void k_oproj(
    const unsigned short* __restrict__ Op, const float* __restrict__ MS,
    const float* __restrict__ Wo, const float* __restrict__ bo,
    float* __restrict__ out) {
  __shared__ unsigned short Al[64 * 256];
  __shared__ unsigned short Bl[64 * 256];
  const int m0 = blockIdx.x * 64, n0 = blockIdx.y * 64;
  const int tid = threadIdx.x;
#pragma unroll
  for (int it = 0; it < 8; ++it) {
    int C = it * 256 + tid;
    int row = C >> 5, lc = C & 31;
    size_t m = (size_t)(m0 + row);
    uint4 pa;
    if (NH > 1) {
      int hh = lc >> 2;
      float ssum = 0.f;
#pragma unroll
      for (int sl = 0; sl < NH; ++sl) ssum += MS[(size_t)sl * 65536 + m * 8 + hh];
      float rinv = 1.0f / ssum;
      float acc8[8] = {};
#pragma unroll
      for (int sl = 0; sl < NH; ++sl) {
        uint4 a0 = *(const uint4*)&Op[(size_t)sl * NEL + m * 256 + lc * 8];
        const unsigned* ap = (const unsigned*)&a0;
#pragma unroll
        for (int j = 0; j < 4; ++j) {
          acc8[2 * j + 0] += bf2f((unsigned short)(ap[j] & 0xffff));
          acc8[2 * j + 1] += bf2f((unsigned short)(ap[j] >> 16));
        }
      }
      unsigned* op = (unsigned*)&pa;
#pragma unroll
      for (int j = 0; j < 4; ++j)
        op[j] = cvtpk(acc8[2 * j] * rinv, acc8[2 * j + 1] * rinv);
    } else {
      pa = *(const uint4*)&Op[m * 256 + lc * 8];
    }
    *(uint4*)&Al[row * 256 + ((lc ^ (row & 7)) * 8)] = pa;
    const float4* gb = (const float4*)(Wo + (size_t)(n0 + row) * 256 + lc * 8);
    float4 b0 = gb[0], b1 = gb[1];
    uint4 pb;
    pb.x = cvtpk(b0.x, b0.y); pb.y = cvtpk(b0.z, b0.w);
    pb.z = cvtpk(b1.x, b1.y); pb.w = cvtpk(b1.z, b1.w);
    *(uint4*)&Bl[row * 256 + ((lc ^ (row & 7)) * 8)] = pb;
  }
  __syncthreads();

  const int w = tid >> 6, l = tid & 63, g = l >> 4, ql = l & 15;
  const int wm = w >> 1, wn = w & 1;
  f32x4 acc[2][2] = {};
#pragma unroll
  for (int kk = 0; kk < 8; ++kk) {
    short8 af[2], bf_[2];
#pragma unroll
    for (int mi = 0; mi < 2; ++mi) {
      int row = wm * 32 + mi * 16 + ql;
      af[mi] = *(const short8*)&Al[row * 256 + (((kk * 4 + g) ^ (row & 7)) * 8)];
    }
#pragma unroll
    for (int ni = 0; ni < 2; ++ni) {
      int row = wn * 32 + ni * 16 + ql;
      bf_[ni] = *(const short8*)&Bl[row * 256 + (((kk * 4 + g) ^ (row & 7)) * 8)];
    }
#pragma unroll
    for (int mi = 0; mi < 2; ++mi)
#pragma unroll
      for (int ni = 0; ni < 2; ++ni)
        acc[mi][ni] = __builtin_amdgcn_mfma_f32_16x16x32_bf16(af[mi], bf_[ni], acc[mi][ni], 0, 0, 0);
  }
#pragma unroll
  for (int ni = 0; ni < 2; ++ni) {
    int n = n0 + wn * 32 + ni * 16 + ql;
    float bs = bo[n];
#pragma unroll
    for (int mi = 0; mi < 2; ++mi) {
      int mb = m0 + wm * 32 + mi * 16 + 4 * g;
      out[(size_t)(mb + 0) * 256 + n] = acc[mi][ni].x + bs;
      out[(size_t)(mb + 1) * 256 + n] = acc[mi][ni].y + bs;
      out[(size_t)(mb + 2) * 256 + n] = acc[mi][ni].z + bs;
      out[(size_t)(mb + 3) * 256 + n] = acc[mi][ni].w + bs;
    }
  }
}

extern "C" void kernel_launch(void* const* d_in, const int* in_sizes, int n_in,
                              void* d_out, int out_size, void* d_ws, size_t ws_size,
                              hipStream_t stream) {
  const float* x    = (const float*)d_in[0];
  const float* oc   = (const float*)d_in[1];
  const float* Wq   = (const float*)d_in[2];
  const float* bq   = (const float*)d_in[3];
  const float* Wk   = (const float*)d_in[4];
  const float* bk   = (const float*)d_in[5];
  const float* Wv   = (const float*)d_in[6];
  const float* bv   = (const float*)d_in[7];
  const float* Wo   = (const float*)d_in[8];
  const float* bo   = (const float*)d_in[9];
  const float* eta  = (const float*)d_in[10];
  const float* beta = (const float*)d_in[11];
  const float* alpha= (const float*)d_in[12];

  unsigned short* Qb  = (unsigned short*)d_ws;
  unsigned short* Kb  = Qb + NEL;
  unsigned short* Vtb = Kb + NEL;
  float* td2 = (float*)(Vtb + NEL);
  float* ocT = td2 + 2048;
  unsigned short* Op = (unsigned short*)(ocT + 4 * 3 * 2048);
  float* out = (float*)d_out;

  const size_t base = 3 * NEL * 2 + (2048 + 4 * 3 * 2048) * 4;
  const size_t need4 = base + 4 * NEL * 2 + (size_t)4 * 65536 * 4;
  const size_t need2 = base + 2 * NEL * 2 + (size_t)2 * 65536 * 4;

  k_tables<<<dim3(8), dim3(256), 0, stream>>>(eta, beta, alpha, oc, td2, ocT);
  k_proj<<<dim3(128, 4, 3), dim3(256), 0, stream>>>(x, Wq, bq, Wk, bk, Wv, bv, Qb, Kb, Vtb);
  if (ws_size >= need4) {
    float* MS = (float*)(Op + 4 * NEL);
    k_attn<4><<<dim3(128, 4), dim3(512), 0, stream>>>(Qb, Kb, Vtb, oc, ocT, td2, Op, MS);
    k_oproj<4><<<dim3(128, 4), dim3(256), 0, stream>>>(Op, MS, Wo, bo, out);
  } else if (ws_size >= need2) {
    float* MS = (float*)(Op + 2 * NEL);
    k_attn<2><<<dim3(64, 4), dim3(512), 0, stream>>>(Qb, Kb, Vtb, oc, ocT, td2, Op, MS);
    k_oproj<2><<<dim3(128, 4), dim3(256), 0, stream>>>(Op, MS, Wo, bo, out);
  } else {
    float* MS = (float*)(Op + NEL);
    k_attn<1><<<dim3(64, 4), dim3(512), 0, stream>>>(Qb, Kb, Vtb, oc, ocT, td2, Op, MS);
    k_oproj<1><<<dim3(128, 4), dim3(256), 0, stream>>>(Op, MS, Wo, bo, out);
  }
}

// Round 21
// 82.297 us; speedup vs baseline: 1.0320x; 1.0320x over previous
//
#include <hip/hip_runtime.h>
#include <stdint.h>

#define TB 2048
#define NEL ((size_t)4 * TB * 256)   // elements of one [B*T,256] bf16 buffer

typedef __attribute__((ext_vector_type(4))) float f32x4;
typedef __attribute__((ext_vector_type(8))) short short8;

__device__ __forceinline__ unsigned short f2bf(float f) {
  union { float f; unsigned u; } v; v.f = f;
  unsigned r = v.u + 0x7fffu + ((v.u >> 16) & 1u);
  return (unsigned short)(r >> 16);
}
__device__ __forceinline__ unsigned cvtpk(float lo, float hi) {
  unsigned r;
  asm("v_cvt_pk_bf16_f32 %0, %1, %2" : "=v"(r) : "v"(lo), "v"(hi));
  return r;
}
__device__ __forceinline__ float bf2f(unsigned short u) {
  union { unsigned u; float f; } v; v.u = ((unsigned)u) << 16;
  return v.f;
}

// ---------------- kernel 1: tables ----------------
// td2[d] = alpha*eta/(1+d^|beta|) * (1/sqrt(32)) * log2(e)   (all scales folded)
// ocT[b][c][t] = oc[b][t][c]
__global__ void k_tables(const float* __restrict__ eta, const float* __restrict__ beta,
                         const float* __restrict__ alpha, const float* __restrict__ oc,
                         float* __restrict__ td2, float* __restrict__ ocT) {
  int i = blockIdx.x * 256 + threadIdx.x;  // 2048 threads
  if (i < TB) {
    float ab = fabsf(beta[0]);
    float dt = powf((float)i, ab);
    td2[i] = alpha[0] * eta[0] / (1.0f + dt) * 0.17677669529663687f * 1.4426950408889634f;
  }
  for (int j = i; j < 4 * 3 * TB; j += 2048) {
    int b = j / (3 * TB);
    int r = j - b * 3 * TB;
    int c = r / TB;
    int t = r - c * TB;
    ocT[j] = oc[((size_t)b * TB + t) * 3 + c];
  }
}

// ---------------- kernel 2: QKV projection ----------------
__global__ __launch_bounds__(256, 2) void k_proj(
    const float* __restrict__ x,
    const float* __restrict__ Wq, const float* __restrict__ bq,
    const float* __restrict__ Wk, const float* __restrict__ bk,
    const float* __restrict__ Wv, const float* __restrict__ bv,
    unsigned short* __restrict__ Qb, unsigned short* __restrict__ Kb,
    unsigned short* __restrict__ Vtb) {
  __shared__ unsigned short Al[64 * 256];
  __shared__ unsigned short Bl[64 * 256];
  const int m0 = blockIdx.x * 64, n0 = blockIdx.y * 64, z = blockIdx.z;
  const int tid = threadIdx.x;
  const float* W = (z == 0) ? Wq : (z == 1) ? Wk : Wv;
  const float* bias = (z == 0) ? bq : (z == 1) ? bk : bv;

#pragma unroll
  for (int it = 0; it < 8; ++it) {
    int C = it * 256 + tid;
    int row = C >> 5, lc = C & 31;
    const float4* ga = (const float4*)(x + (size_t)(m0 + row) * 256 + lc * 8);
    float4 a0 = ga[0], a1 = ga[1];
    uint4 pa;
    pa.x = cvtpk(a0.x, a0.y); pa.y = cvtpk(a0.z, a0.w);
    pa.z = cvtpk(a1.x, a1.y); pa.w = cvtpk(a1.z, a1.w);
    *(uint4*)&Al[row * 256 + ((lc ^ (row & 7)) * 8)] = pa;
    const float4* gb = (const float4*)(W + (size_t)(n0 + row) * 256 + lc * 8);
    float4 b0 = gb[0], b1 = gb[1];
    uint4 pb;
    pb.x = cvtpk(b0.x, b0.y); pb.y = cvtpk(b0.z, b0.w);
    pb.z = cvtpk(b1.x, b1.y); pb.w = cvtpk(b1.z, b1.w);
    *(uint4*)&Bl[row * 256 + ((lc ^ (row & 7)) * 8)] = pb;
  }
  __syncthreads();

  const int w = tid >> 6, l = tid & 63, g = l >> 4, ql = l & 15;
  const int wm = w >> 1, wn = w & 1;
  f32x4 acc[2][2] = {};
#pragma unroll
  for (int kk = 0; kk < 8; ++kk) {
    short8 af[2], bf_[2];
#pragma unroll
    for (int mi = 0; mi < 2; ++mi) {
      int row = wm * 32 + mi * 16 + ql;
      af[mi] = *(const short8*)&Al[row * 256 + (((kk * 4 + g) ^ (row & 7)) * 8)];
    }
#pragma unroll
    for (int ni = 0; ni < 2; ++ni) {
      int row = wn * 32 + ni * 16 + ql;
      bf_[ni] = *(const short8*)&Bl[row * 256 + (((kk * 4 + g) ^ (row & 7)) * 8)];
    }
#pragma unroll
    for (int mi = 0; mi < 2; ++mi)
#pragma unroll
      for (int ni = 0; ni < 2; ++ni)
        acc[mi][ni] = __builtin_amdgcn_mfma_f32_16x16x32_bf16(af[mi], bf_[ni], acc[mi][ni], 0, 0, 0);
  }

#pragma unroll
  for (int ni = 0; ni < 2; ++ni) {
    int n = n0 + wn * 32 + ni * 16 + ql;
    float bs = bias[n];
#pragma unroll
    for (int mi = 0; mi < 2; ++mi) {
      int mb = m0 + wm * 32 + mi * 16 + 4 * g;
      f32x4 v = acc[mi][ni];
      v.x += bs; v.y += bs; v.z += bs; v.w += bs;
      if (z == 2) {
        int batch = mb >> 11, t = mb & 2047;
        uint2 pv; pv.x = cvtpk(v.x, v.y); pv.y = cvtpk(v.z, v.w);
        *(uint2*)&Vtb[(size_t)(batch * 256 + n) * 2048 + t] = pv;
      } else {
        unsigned short* dst = (z == 0) ? Qb : Kb;
        dst[(size_t)(mb + 0) * 256 + n] = f2bf(v.x);
        dst[(size_t)(mb + 1) * 256 + n] = f2bf(v.y);
        dst[(size_t)(mb + 2) * 256 + n] = f2bf(v.z);
        dst[(size_t)(mb + 3) * 256 + n] = f2bf(v.w);
      }
    }
  }
}

// ---------------- kernel 3: fused causal attention with prior ----------------
// QB=32, 512 threads = 8 waves = 8 heads. No online max (|score*prior| small:
// exp2 safe in f32; ratios exact). Pl LDS transpose + verified 16x16x32 PV,
// K/V direct from global (L2-resident). LDS 48KB. ONE barrier per k-step.
// BALANCED SCHEDULE: pair qt=i with qt=63-i (33 steps per pair); each block
// runs slot j's 1/NSLOT share of BOTH q-tiles -> all blocks equal work.
// NSLOT=4, grid x=128 -> ip=bx>>2 in [0,31]: each (qt,slot) exactly once.
template <int NSLOT>
__global__ __launch_bounds__(512, 4) void k_attn(
    const unsigned short* __restrict__ Qb, const unsigned short* __restrict__ Kb,
    const unsigned short* __restrict__ Vtb, const float* __restrict__ oc,
    const float* __restrict__ ocT, const float* __restrict__ td2,
    unsigned short* __restrict__ Op, float* __restrict__ MS) {
  __shared__ unsigned short Pl[8][32 * 64]; // 32KB per-wave P [q][k]
  __shared__ float Pr[2][32 * 64];          // 16KB dbuf prior [q][k]
  const int bx = blockIdx.x, bb = blockIdx.y;
  const int ip   = (NSLOT == 4) ? (bx >> 2) : (NSLOT == 2) ? (bx >> 1) : bx;
  const int slot = (NSLOT == 4) ? (bx & 3)  : (NSLOT == 2) ? (bx & 1)  : 0;
  const int tid = threadIdx.x;
  const int w = tid >> 6, l = tid & 63, g = l >> 4, ql = l & 15;
  const int h = w;
  const f32x4 zero4 = {0.f, 0.f, 0.f, 0.f};
  const int pq = tid & 31, pck = tid >> 5;  // prior mapping: q-row, 4-wide k-chunk

  int par = 0;  // Pr buffer parity, carried across segments

#pragma unroll 1
  for (int seg = 0; seg < 2; ++seg) {
    if (NSLOT == 1 && seg == 1) break;
    const int qt = (NSLOT == 1) ? (63 - bx) : (seg ? ip : (63 - ip));
    const int q0 = qt * 32;
    const int nst = (qt + 2) >> 1;
    const int sb = (NSLOT == 1) ? 0 : (slot * nst) / NSLOT;
    const int se = (NSLOT == 1) ? nst : ((slot + 1) * nst) / NSLOT;

    short8 qf[2];
#pragma unroll
    for (int qb = 0; qb < 2; ++qb)
      qf[qb] = *(const short8*)&Qb[(size_t)(bb * TB + q0 + qb * 16 + ql) * 256 + h * 32 + 8 * g];

    const float oq0 = oc[(size_t)(bb * TB + q0 + pq) * 3 + 0];
    const float oq1 = oc[(size_t)(bb * TB + q0 + pq) * 3 + 1];
    const float oq2 = oc[(size_t)(bb * TB + q0 + pq) * 3 + 2];

    f32x4 oacc[2][2] = {};   // [db][qb]
    float srow[2] = {0.f, 0.f};

    for (int st = sb; st < se; ++st, par ^= 1) {
      const int k0 = st * 64;
      // K fragments for THIS step, direct from global (L2-resident)
      short8 kf0 = *(const short8*)&Kb[(size_t)(bb * TB + k0 + 0 * 16 + ql) * 256 + h * 32 + 8 * g];
      short8 kf1 = *(const short8*)&Kb[(size_t)(bb * TB + k0 + 1 * 16 + ql) * 256 + h * 32 + 8 * g];
      short8 kf2 = *(const short8*)&Kb[(size_t)(bb * TB + k0 + 2 * 16 + ql) * 256 + h * 32 + 8 * g];
      short8 kf3 = *(const short8*)&Kb[(size_t)(bb * TB + k0 + 3 * 16 + ql) * 256 + h * 32 + 8 * g];
      // prior tile [32q][64k] (shared by all 8 heads), vectorized ocT loads
      {
        const float* o0 = &ocT[(size_t)bb * 3 * TB + k0 + pck * 4];
        float4 a = *(const float4*)o0;
        float4 b2 = *(const float4*)(o0 + TB);
        float4 c2 = *(const float4*)(o0 + 2 * TB);
        const int qi = q0 + pq - k0 - pck * 4;
        float pv0, pv1, pv2, pv3;
        {
          float d0 = oq0 - a.x, d1 = oq1 - b2.x, d2 = oq2 - c2.x;
          int dd = qi; dd = dd < 0 ? -dd : dd;
          pv0 = td2[dd] * __expf(-(d0 * d0 + d1 * d1 + d2 * d2));
        }
        {
          float d0 = oq0 - a.y, d1 = oq1 - b2.y, d2 = oq2 - c2.y;
          int dd = qi - 1; dd = dd < 0 ? -dd : dd;
          pv1 = td2[dd] * __expf(-(d0 * d0 + d1 * d1 + d2 * d2));
        }
        {
          float d0 = oq0 - a.z, d1 = oq1 - b2.z, d2 = oq2 - c2.z;
          int dd = qi - 2; dd = dd < 0 ? -dd : dd;
          pv2 = td2[dd] * __expf(-(d0 * d0 + d1 * d1 + d2 * d2));
        }
        {
          float d0 = oq0 - a.w, d1 = oq1 - b2.w, d2 = oq2 - c2.w;
          int dd = qi - 3; dd = dd < 0 ? -dd : dd;
          pv3 = td2[dd] * __expf(-(d0 * d0 + d1 * d1 + d2 * d2));
        }
        f32x4 pvv = {pv0, pv1, pv2, pv3};
        *(f32x4*)&Pr[par][pq * 64 + ((pck ^ (pq & 15)) * 4)] = pvv;
      }
      __syncthreads();

      // ---- S^T = mfma(K, Q): lane owns q = qb*16+ql, k = 16*kb+4*g+reg ----
      const bool diag = (k0 + 64 > q0);
#pragma unroll
      for (int qb = 0; qb < 2; ++qb) {
        const int qq = qb * 16 + ql;
        const int qg = q0 + qq;
        f32x4 s[4];
        s[0] = __builtin_amdgcn_mfma_f32_16x16x32_bf16(kf0, qf[qb], zero4, 0, 0, 0);
        s[1] = __builtin_amdgcn_mfma_f32_16x16x32_bf16(kf1, qf[qb], zero4, 0, 0, 0);
        s[2] = __builtin_amdgcn_mfma_f32_16x16x32_bf16(kf2, qf[qb], zero4, 0, 0, 0);
        s[3] = __builtin_amdgcn_mfma_f32_16x16x32_bf16(kf3, qf[qb], zero4, 0, 0, 0);
        float ssum = 0.f;
#pragma unroll
        for (int kb = 0; kb < 4; ++kb) {
          f32x4 pr = *(const f32x4*)&Pr[par][qq * 64 + (((kb * 4 + g) ^ ql) * 4)];
          f32x4 s2;
          s2.x = s[kb].x * pr.x; s2.y = s[kb].y * pr.y;
          s2.z = s[kb].z * pr.z; s2.w = s[kb].w * pr.w;
          if (diag) {
            int kbase = k0 + kb * 16 + 4 * g;
            if (kbase + 0 > qg) s2.x = -__builtin_inff();
            if (kbase + 1 > qg) s2.y = -__builtin_inff();
            if (kbase + 2 > qg) s2.z = -__builtin_inff();
            if (kbase + 3 > qg) s2.w = -__builtin_inff();
          }
          f32x4 p;
          p.x = exp2f(s2.x); p.y = exp2f(s2.y);
          p.z = exp2f(s2.z); p.w = exp2f(s2.w);
          ssum += (p.x + p.y) + (p.z + p.w);
          uint2 pp; pp.x = cvtpk(p.x, p.y); pp.y = cvtpk(p.z, p.w);
          int c16 = 2 * kb + (g >> 1);
          *(uint2*)&Pl[w][qq * 64 + ((c16 ^ (qq & 7)) * 8) + (g & 1) * 4] = pp;
        }
        srow[qb] += ssum;
      }
      // this wave's P writes -> visible to its own cross-lane reads
      asm volatile("s_waitcnt lgkmcnt(0)" ::: "memory");

      // ---- PV: O^T[d][q] += sum_k V^T[d][k] * P[q][k]; V direct from global --
#pragma unroll
      for (int ks = 0; ks < 2; ++ks) {
        short8 pf0 = *(const short8*)&Pl[w][(ql) * 64 + (((ks * 4 + g) ^ (ql & 7)) * 8)];
        short8 pf1 = *(const short8*)&Pl[w][(16 + ql) * 64 + (((ks * 4 + g) ^ (ql & 7)) * 8)];
        short8 vf0 = *(const short8*)&Vtb[(size_t)(bb * 256 + h * 32 + ql) * 2048 + k0 + ks * 32 + 8 * g];
        short8 vf1 = *(const short8*)&Vtb[(size_t)(bb * 256 + h * 32 + 16 + ql) * 2048 + k0 + ks * 32 + 8 * g];
        oacc[0][0] = __builtin_amdgcn_mfma_f32_16x16x32_bf16(vf0, pf0, oacc[0][0], 0, 0, 0);
        oacc[0][1] = __builtin_amdgcn_mfma_f32_16x16x32_bf16(vf0, pf1, oacc[0][1], 0, 0, 0);
        oacc[1][0] = __builtin_amdgcn_mfma_f32_16x16x32_bf16(vf1, pf0, oacc[1][0], 0, 0, 0);
        oacc[1][1] = __builtin_amdgcn_mfma_f32_16x16x32_bf16(vf1, pf1, oacc[1][1], 0, 0, 0);
      }
    }

    // ---- epilogue for this segment ----
#pragma unroll
    for (int qb = 0; qb < 2; ++qb) {
      float s_ = srow[qb];
      s_ += __shfl_xor(s_, 16);
      s_ += __shfl_xor(s_, 32);
      int qq = qb * 16 + ql;
      size_t m = (size_t)bb * TB + q0 + qq;
      if (NSLOT == 1) {
        float rinv = 1.0f / s_;
#pragma unroll
        for (int db = 0; db < 2; ++db) {
          f32x4 v = oacc[db][qb];
          uint2 pv2;
          pv2.x = cvtpk(v.x * rinv, v.y * rinv);
          pv2.y = cvtpk(v.z * rinv, v.w * rinv);
          *(uint2*)&Op[m * 256 + h * 32 + db * 16 + 4 * g] = pv2;
        }
      } else {
#pragma unroll
        for (int db = 0; db < 2; ++db) {
          f32x4 v = oacc[db][qb];
          uint2 pv2;
          pv2.x = cvtpk(v.x, v.y);
          pv2.y = cvtpk(v.z, v.w);
          *(uint2*)&Op[(size_t)slot * NEL + m * 256 + h * 32 + db * 16 + 4 * g] = pv2;
        }
        if (g == 0) MS[(size_t)slot * 65536 + m * 8 + h] = s_;
      }
    }
  }
}

// ---------------- kernel 4: output projection (+ NH-way merge folded in) ----
template <int NH>
__global__ __launch_bounds__(256, 2) void k_oproj(
    const unsigned short* __restrict__ Op, const float* __restrict__ MS,
    const float* __restrict__ Wo, const float* __restrict__ bo,
    float* __restrict__ out) {
  __shared__ unsigned short Al[64 * 256];
  __shared__ unsigned short Bl[64 * 256];
  const int m0 = blockIdx.x * 64, n0 = blockIdx.y * 64;
  const int tid = threadIdx.x;
#pragma unroll
  for (int it = 0; it < 8; ++it) {
    int C = it * 256 + tid;
    int row = C >> 5, lc = C & 31;
    size_t m = (size_t)(m0 + row);
    uint4 pa;
    if (NH > 1) {
      int hh = lc >> 2;
      float ssum = 0.f;
#pragma unroll
      for (int sl = 0; sl < NH; ++sl) ssum += MS[(size_t)sl * 65536 + m * 8 + hh];
      float rinv = 1.0f / ssum;
      float acc8[8] = {};
#pragma unroll
      for (int sl = 0; sl < NH; ++sl) {
        uint4 a0 = *(const uint4*)&Op[(size_t)sl * NEL + m * 256 + lc * 8];
        const unsigned* ap = (const unsigned*)&a0;
#pragma unroll
        for (int j = 0; j < 4; ++j) {
          acc8[2 * j + 0] += bf2f((unsigned short)(ap[j] & 0xffff));
          acc8[2 * j + 1] += bf2f((unsigned short)(ap[j] >> 16));
        }
      }
      unsigned* op = (unsigned*)&pa;
#pragma unroll
      for (int j = 0; j < 4; ++j)
        op[j] = cvtpk(acc8[2 * j] * rinv, acc8[2 * j + 1] * rinv);
    } else {
      pa = *(const uint4*)&Op[m * 256 + lc * 8];
    }
    *(uint4*)&Al[row * 256 + ((lc ^ (row & 7)) * 8)] = pa;
    const float4* gb = (const float4*)(Wo + (size_t)(n0 + row) * 256 + lc * 8);
    float4 b0 = gb[0], b1 = gb[1];
    uint4 pb;
    pb.x = cvtpk(b0.x, b0.y); pb.y = cvtpk(b0.z, b0.w);
    pb.z = cvtpk(b1.x, b1.y); pb.w = cvtpk(b1.z, b1.w);
    *(uint4*)&Bl[row * 256 + ((lc ^ (row & 7)) * 8)] = pb;
  }
  __syncthreads();

  const int w = tid >> 6, l = tid & 63, g = l >> 4, ql = l & 15;
  const int wm = w >> 1, wn = w & 1;
  f32x4 acc[2][2] = {};
#pragma unroll
  for (int kk = 0; kk < 8; ++kk) {
    short8 af[2], bf_[2];
#pragma unroll
    for (int mi = 0; mi < 2; ++mi) {
      int row = wm * 32 + mi * 16 + ql;
      af[mi] = *(const short8*)&Al[row * 256 + (((kk * 4 + g) ^ (row & 7)) * 8)];
    }
#pragma unroll
    for (int ni = 0; ni < 2; ++ni) {
      int row = wn * 32 + ni * 16 + ql;
      bf_[ni] = *(const short8*)&Bl[row * 256 + (((kk * 4 + g) ^ (row & 7)) * 8)];
    }
#pragma unroll
    for (int mi = 0; mi < 2; ++mi)
#pragma unroll
      for (int ni = 0; ni < 2; ++ni)
        acc[mi][ni] = __builtin_amdgcn_mfma_f32_16x16x32_bf16(af[mi], bf_[ni], acc[mi][ni], 0, 0, 0);
  }
#pragma unroll
  for (int ni = 0; ni < 2; ++ni) {
    int n = n0 + wn * 32 + ni * 16 + ql;
    float bs = bo[n];
#pragma unroll
    for (int mi = 0; mi < 2; ++mi) {
      int mb = m0 + wm * 32 + mi * 16 + 4 * g;
      out[(size_t)(mb + 0) * 256 + n] = acc[mi][ni].x + bs;
      out[(size_t)(mb + 1) * 256 + n] = acc[mi][ni].y + bs;
      out[(size_t)(mb + 2) * 256 + n] = acc[mi][ni].z + bs;
      out[(size_t)(mb + 3) * 256 + n] = acc[mi][ni].w + bs;
    }
  }
}

extern "C" void kernel_launch(void* const* d_in, const int* in_sizes, int n_in,
                              void* d_out, int out_size, void* d_ws, size_t ws_size,
                              hipStream_t stream) {
  const float* x    = (const float*)d_in[0];
  const float* oc   = (const float*)d_in[1];
  const float* Wq   = (const float*)d_in[2];
  const float* bq   = (const float*)d_in[3];
  const float* Wk   = (const float*)d_in[4];
  const float* bk   = (const float*)d_in[5];
  const float* Wv   = (const float*)d_in[6];
  const float* bv   = (const float*)d_in[7];
  const float* Wo   = (const float*)d_in[8];
  const float* bo   = (const float*)d_in[9];
  const float* eta  = (const float*)d_in[10];
  const float* beta = (const float*)d_in[11];
  const float* alpha= (const float*)d_in[12];

  unsigned short* Qb  = (unsigned short*)d_ws;
  unsigned short* Kb  = Qb + NEL;
  unsigned short* Vtb = Kb + NEL;
  float* td2 = (float*)(Vtb + NEL);
  float* ocT = td2 + 2048;
  unsigned short* Op = (unsigned short*)(ocT + 4 * 3 * 2048);
  float* out = (float*)d_out;

  const size_t base = 3 * NEL * 2 + (2048 + 4 * 3 * 2048) * 4;
  const size_t need4 = base + 4 * NEL * 2 + (size_t)4 * 65536 * 4;
  const size_t need2 = base + 2 * NEL * 2 + (size_t)2 * 65536 * 4;

  k_tables<<<dim3(8), dim3(256), 0, stream>>>(eta, beta, alpha, oc, td2, ocT);
  k_proj<<<dim3(128, 4, 3), dim3(256), 0, stream>>>(x, Wq, bq, Wk, bk, Wv, bv, Qb, Kb, Vtb);
  if (ws_size >= need4) {
    float* MS = (float*)(Op + 4 * NEL);
    k_attn<4><<<dim3(128, 4), dim3(512), 0, stream>>>(Qb, Kb, Vtb, oc, ocT, td2, Op, MS);
    k_oproj<4><<<dim3(128, 4), dim3(256), 0, stream>>>(Op, MS, Wo, bo, out);
  } else if (ws_size >= need2) {
    float* MS = (float*)(Op + 2 * NEL);
    k_attn<2><<<dim3(64, 4), dim3(512), 0, stream>>>(Qb, Kb, Vtb, oc, ocT, td2, Op, MS);
    k_oproj<2><<<dim3(128, 4), dim3(256), 0, stream>>>(Op, MS, Wo, bo, out);
  } else {
    float* MS = (float*)(Op + NEL);
    k_attn<1><<<dim3(64, 4), dim3(512), 0, stream>>>(Qb, Kb, Vtb, oc, ocT, td2, Op, MS);
    k_oproj<1><<<dim3(128, 4), dim3(256), 0, stream>>>(Op, MS, Wo, bo, out);
  }
}